// Round 1
// baseline (405.299 us; speedup 1.0000x reference)
//
#include <hip/hip_runtime.h>
#include <hip/hip_bf16.h>
#include <math.h>

#define NN 16384
#define DEG 20
#define RMAXF 3.5f
#define NGRP 5   // groups of 16 edges per block (80 edges = 4 nodes)

typedef __attribute__((ext_vector_type(8))) short short8;
typedef __attribute__((ext_vector_type(4))) float f32x4;

// soft_unit_step: exp(-1/x) for x>0 else 0
__device__ __forceinline__ float su_f(float x) {
    return x > 0.0f ? __expf(-1.0f / x) : 0.0f;
}
__device__ __forceinline__ ushort f2bf(float x) {
    __hip_bfloat16 h = __float2bfloat16(x);
    return *reinterpret_cast<ushort*>(&h);
}

// ---------------------------------------------------------------------------
// Round-12 structure: the MFMA D-matrix is consumed IN REGISTERS per path.
// Wave w's accumulators hold exactly TP path p=w:
//   col = (wave*4+jj)*16+n  ==  path=wave, i=2*jj+hi, o=n&7;  rows el=4*qd+r.
// All TP outputs + the logit are linear in per-path partials:
//   wave0: sum_i a_i w0[i][o]      (ss->s)      -> s_vA[.][o], logit via mq[o]
//   wave1: sum_i b_i w1[i][o]      (vv->s)      -> s_vB[.][o], logit via mq[o]
//   wave2: U=sum_i a_i w2[i][o]; out=s1[c]*U    -> s_vA[.][8+3o+c], logit via mqs1
//   wave3: T_c=sum_i gv[i][c] w3[i][o]          -> s_vB[.][8+3o+c], logit via mq[8+3o+c]
// s_w (33.4 KB) + barrier 3 are gone; LDS 52.7 -> 31.6 KB (3 -> 4-5 blocks/CU).
// Logit partials: shfl-reduce over the 16-lane quad group -> s_lgp[el][wave],
// finalized by 16 threads after b3.  Norm 0.25 folded into epilogue coef;
// logit norm 0.25/(8*sqrt2) folded into finalize.
// Relies on edst[e] == e/20 (contiguous segments; exploited since round 1).
// ---------------------------------------------------------------------------
__global__ __launch_bounds__(256, 4) void edge_kernel(
    const float* __restrict__ f,   const float* __restrict__ pos,
    const float* __restrict__ Wqs, const float* __restrict__ Wqv,
    const float* __restrict__ Wds, const float* __restrict__ Wdv,
    const float* __restrict__ Wk1, const float* __restrict__ Wv1,
    const float* __restrict__ Wk2, const float* __restrict__ Wv2,
    const int* __restrict__ esrc,  float* __restrict__ out)
{
    __shared__ __align__(16) ushort s_hb[2][16][64];  // 4 KB bf16 h, XOR-swizzled
    __shared__ __align__(16) float s_g[16][36];       // 2.25 KB gathered f[src]
    __shared__ float s_emb[16][10];
    __shared__ float s_s1[16][4];
    __shared__ float s_b[16][9];                      // b_i = (gv_i . s1)/sqrt3
    __shared__ float s_mqs1[16][9];                   // sum_c mq[8+3o+c]*s1[c]
    __shared__ float s_vA[80][34];                    // v-partials, paths 0 & 2
    __shared__ float s_vB[80][34];                    // v-partials, paths 1 & 3
    __shared__ float s_lg[80];                        // per-edge logits
    __shared__ float s_cut[80];                       // per-edge cutoff
    __shared__ float s_lgp[16][4];                    // per-wave logit partials
    __shared__ float s_mqn[4][32];                    // mq for block's 4 nodes
    // total ~31.6 KB

    const int t = threadIdx.x;
    const int wave = t >> 6, lane = t & 63;
    const int qd = lane >> 4, n = lane & 15;
    const int o8 = n & 7, hi = n >> 3;
    const int n0 = blockIdx.x * 4;                    // first node of block
    const int E0 = n0 * DEG;                          // first edge of block

    // ---- prologue A: mq for the block's 4 dst nodes (verbatim prep math) ----
    if (t < 128) {
        int nd = t >> 5, idx = t & 31;
        const float* fr = f + (size_t)(n0 + nd) * 32;
        const float inv8 = 0.35355339059327373f; // 1/sqrt(8)
        float o_ = 0.0f;
        if (idx < 8) {
            int j = idx;
            #pragma unroll
            for (int i = 0; i < 8; i++) {
                float qs = 0.0f;
                #pragma unroll
                for (int a = 0; a < 8; a++) qs = fmaf(fr[a], Wqs[a * 8 + i], qs);
                o_ = fmaf(qs * inv8, Wds[i * 8 + j], o_);
            }
        } else {
            int kk = idx - 8;
            int j = kk / 3, c = kk - 3 * j;
            #pragma unroll
            for (int i = 0; i < 8; i++) {
                float qv = 0.0f;
                #pragma unroll
                for (int a = 0; a < 8; a++) qv = fmaf(fr[8 + 3 * a + c], Wqv[a * 8 + i], qv);
                o_ = fmaf(qv * inv8, Wdv[i * 8 + j], o_);
            }
            o_ *= 0.5773502691896258f; // 1/sqrt(3)
        }
        s_mqn[nd][idx] = o_;
    }

    // ---- prologue B: W1 rows for this lane (20 regs) ----
    float wk1r[10], wv1r[10];
    #pragma unroll
    for (int j = 0; j < 10; j++) {
        wk1r[j] = Wk1[j * 64 + lane];
        wv1r[j] = Wv1[j * 64 + lane];
    }

    // ---- prologue C: B fragments packed directly from W2 (both nets) ----
    short8 breg[2][2][4];
    #pragma unroll
    for (int net = 0; net < 2; net++) {
        const float* W2 = net ? Wv2 : Wk2;
        #pragma unroll
        for (int s = 0; s < 2; s++)
            #pragma unroll
            for (int jj = 0; jj < 4; jj++) {
                int col = (wave * 4 + jj) * 16 + n;
                union { ushort u[8]; short8 v; } bf;
                #pragma unroll
                for (int j = 0; j < 8; j++) {
                    int k0 = s * 32 + qd * 8 + j;
                    bf.u[j] = f2bf(W2[k0 * 256 + col] * 0.125f);
                }
                breg[net][s][jj] = bf.v;
            }
    }

    for (int g = 0; g < NGRP; g++) {
        const int le0 = g * 16;            // local edge base
        const int e0 = E0 + le0;

        // ---- phase A: geometry + radial basis, 11 roles per edge ----
        {
            int e = t >> 4, role = t & 15;
            if (role < 11) {
                int s = esrc[e0 + e];
                int d = n0 + (le0 + e) / DEG;  // edst[e] == e/20
                float vx = pos[s * 3 + 0] - pos[d * 3 + 0];
                float vy = pos[s * 3 + 1] - pos[d * 3 + 1];
                float vz = pos[s * 3 + 2] - pos[d * 3 + 2];
                float r = sqrtf(vx * vx + vy * vy + vz * vz);
                if (role < 10) {
                    const float step = RMAXF / 11.0f;
                    const float invstep = 11.0f / RMAXF;
                    const float K = 26.66929988626f; // 1.14136*e^2*sqrt(10)
                    float dd = (r - step * (float)(role + 1)) * invstep;
                    s_emb[e][role] = K * su_f(dd + 1.0f) * su_f(1.0f - dd);
                } else {
                    float invr = 1.0f / r;
                    const float sqrt3 = 1.7320508075688772f;
                    s_s1[e][0] = sqrt3 * vx * invr;
                    s_s1[e][1] = sqrt3 * vy * invr;
                    s_s1[e][2] = sqrt3 * vz * invr;
                    s_cut[le0 + e] = su_f(10.0f * (1.0f - r / RMAXF));
                }
            }
        }
        // ---- phase A2: stage gathered f[src] rows (float4, threads 0..127) ----
        if (t < 128) {
            int el = t >> 3, c4 = t & 7;
            int s = esrc[e0 + el];
            float4 x = *reinterpret_cast<const float4*>(f + (size_t)s * 32 + c4 * 4);
            *reinterpret_cast<float4*>(&s_g[el][c4 * 4]) = x;
        }
        __syncthreads(); // b1

        // ---- phase B: GEMM1 (W1 in regs) + silu -> s_hb; plus s_b, s_mqs1 ----
        {
            const float invsq10 = 0.31622776601683794f; // 1/sqrt(10)
            #pragma unroll
            for (int e = 0; e < 4; e++) {
                int el = wave * 4 + e;
                float ak = 0.0f, av = 0.0f;
                #pragma unroll
                for (int j = 0; j < 10; j++) {
                    float ej = s_emb[el][j];
                    ak = fmaf(ej, wk1r[j], ak);
                    av = fmaf(ej, wv1r[j], av);
                }
                ak *= invsq10; av *= invsq10;
                float hk = ak / (1.0f + __expf(-ak));
                float hv = av / (1.0f + __expf(-av));
                int pos_ = (((lane >> 3) ^ (el & 7)) << 3) | (lane & 7);
                s_hb[0][el][pos_] = f2bf(hk);
                s_hb[1][el][pos_] = f2bf(hv);
            }
            int u = t & 127, el = u >> 3, k = u & 7;
            if (t < 128) {
                const float inv_sqrt3 = 0.5773502691896258f;
                s_b[el][k] = (s_g[el][8 + 3 * k + 0] * s_s1[el][0] +
                              s_g[el][8 + 3 * k + 1] * s_s1[el][1] +
                              s_g[el][8 + 3 * k + 2] * s_s1[el][2]) * inv_sqrt3;
            } else {
                int nd = (le0 + el) / DEG;
                s_mqs1[el][k] = s_mqn[nd][8 + 3 * k + 0] * s_s1[el][0] +
                                s_mqn[nd][8 + 3 * k + 1] * s_s1[el][1] +
                                s_mqn[nd][8 + 3 * k + 2] * s_s1[el][2];
            }
        }
        __syncthreads(); // b2

        // ---- phase C+D': MFMA, consumed per-path from registers ----
        {
            int el_[4], le_[4], nd_[4];
            #pragma unroll
            for (int r = 0; r < 4; r++) {
                el_[r] = 4 * qd + r;
                le_[r] = le0 + el_[r];
                nd_[r] = le_[r] / DEG;
            }

            // x[r][jj]: per-lane TP input for waves 0..2 (i = 2*jj + hi)
            float x[4][4];
            if (wave < 3) {
                if (wave == 1) {
                    #pragma unroll
                    for (int r = 0; r < 4; r++)
                        #pragma unroll
                        for (int jj = 0; jj < 4; jj++)
                            x[r][jj] = s_b[el_[r]][2 * jj + hi];
                } else {
                    #pragma unroll
                    for (int r = 0; r < 4; r++)
                        #pragma unroll
                        for (int jj = 0; jj < 4; jj++)
                            x[r][jj] = s_g[el_[r]][2 * jj + hi];
                }
            }

            float lgK[4];
            // ===== k-net pass (logit partials only; k never materialized) =====
            {
                short8 ka0 = *(const short8*)&s_hb[0][n][(qd ^ o8) << 3];
                short8 ka1 = *(const short8*)&s_hb[0][n][((4 + qd) ^ o8) << 3];
                if (wave < 3) {
                    float dot[4] = {0.f, 0.f, 0.f, 0.f};
                    #pragma unroll
                    for (int jj = 0; jj < 4; jj++) {
                        f32x4 d = {0.f, 0.f, 0.f, 0.f};
                        d = __builtin_amdgcn_mfma_f32_16x16x32_bf16(ka0, breg[0][0][jj], d, 0, 0, 0);
                        d = __builtin_amdgcn_mfma_f32_16x16x32_bf16(ka1, breg[0][1][jj], d, 0, 0, 0);
                        #pragma unroll
                        for (int r = 0; r < 4; r++)
                            dot[r] = fmaf(x[r][jj], d[r], dot[r]);
                    }
                    if (wave == 2) {
                        #pragma unroll
                        for (int r = 0; r < 4; r++) lgK[r] = dot[r] * s_mqs1[el_[r]][o8];
                    } else {
                        #pragma unroll
                        for (int r = 0; r < 4; r++) lgK[r] = dot[r] * s_mqn[nd_[r]][o8];
                    }
                } else { // wave 3: fold mq into gv on the fly
                    float mq0[4], mq1[4], mq2[4];
                    #pragma unroll
                    for (int r = 0; r < 4; r++) {
                        mq0[r] = s_mqn[nd_[r]][8 + 3 * o8 + 0];
                        mq1[r] = s_mqn[nd_[r]][8 + 3 * o8 + 1];
                        mq2[r] = s_mqn[nd_[r]][8 + 3 * o8 + 2];
                    }
                    float acc[4] = {0.f, 0.f, 0.f, 0.f};
                    #pragma unroll
                    for (int jj = 0; jj < 4; jj++) {
                        f32x4 d = {0.f, 0.f, 0.f, 0.f};
                        d = __builtin_amdgcn_mfma_f32_16x16x32_bf16(ka0, breg[0][0][jj], d, 0, 0, 0);
                        d = __builtin_amdgcn_mfma_f32_16x16x32_bf16(ka1, breg[0][1][jj], d, 0, 0, 0);
                        int i = 2 * jj + hi;
                        #pragma unroll
                        for (int r = 0; r < 4; r++) {
                            float ym = s_g[el_[r]][8 + 3 * i + 0] * mq0[r]
                                     + s_g[el_[r]][8 + 3 * i + 1] * mq1[r]
                                     + s_g[el_[r]][8 + 3 * i + 2] * mq2[r];
                            acc[r] = fmaf(ym, d[r], acc[r]);
                        }
                    }
                    #pragma unroll
                    for (int r = 0; r < 4; r++) lgK[r] = acc[r];
                }
            }
            // logit partial reduce over 16-lane quad group -> s_lgp[el][wave]
            #pragma unroll
            for (int r = 0; r < 4; r++) {
                float v = lgK[r];
                v += __shfl_xor(v, 1);
                v += __shfl_xor(v, 2);
                v += __shfl_xor(v, 4);
                v += __shfl_xor(v, 8);
                if (n == 0) s_lgp[4 * qd + r][wave] = v;
            }
            // ===== v-net pass =====
            {
                short8 va0 = *(const short8*)&s_hb[1][n][(qd ^ o8) << 3];
                short8 va1 = *(const short8*)&s_hb[1][n][((4 + qd) ^ o8) << 3];
                if (wave < 2) { // paths 0 (->s_vA) and 1 (->s_vB), scalar comps
                    float sv[4] = {0.f, 0.f, 0.f, 0.f};
                    #pragma unroll
                    for (int jj = 0; jj < 4; jj++) {
                        f32x4 d = {0.f, 0.f, 0.f, 0.f};
                        d = __builtin_amdgcn_mfma_f32_16x16x32_bf16(va0, breg[1][0][jj], d, 0, 0, 0);
                        d = __builtin_amdgcn_mfma_f32_16x16x32_bf16(va1, breg[1][1][jj], d, 0, 0, 0);
                        #pragma unroll
                        for (int r = 0; r < 4; r++)
                            sv[r] = fmaf(x[r][jj], d[r], sv[r]);
                    }
                    #pragma unroll
                    for (int r = 0; r < 4; r++) {
                        float v = sv[r] + __shfl_xor(sv[r], 8);
                        if (n < 8) {
                            if (wave == 0) s_vA[le_[r]][o8] = v;
                            else           s_vB[le_[r]][o8] = v;
                        }
                    }
                } else if (wave == 2) { // path 2: U then *s1[c]
                    float U[4] = {0.f, 0.f, 0.f, 0.f};
                    #pragma unroll
                    for (int jj = 0; jj < 4; jj++) {
                        f32x4 d = {0.f, 0.f, 0.f, 0.f};
                        d = __builtin_amdgcn_mfma_f32_16x16x32_bf16(va0, breg[1][0][jj], d, 0, 0, 0);
                        d = __builtin_amdgcn_mfma_f32_16x16x32_bf16(va1, breg[1][1][jj], d, 0, 0, 0);
                        #pragma unroll
                        for (int r = 0; r < 4; r++)
                            U[r] = fmaf(x[r][jj], d[r], U[r]);
                    }
                    #pragma unroll
                    for (int r = 0; r < 4; r++) {
                        float u = U[r] + __shfl_xor(U[r], 8);
                        if (n < 8) {
                            s_vA[le_[r]][8 + 3 * o8 + 0] = s_s1[el_[r]][0] * u;
                            s_vA[le_[r]][8 + 3 * o8 + 1] = s_s1[el_[r]][1] * u;
                            s_vA[le_[r]][8 + 3 * o8 + 2] = s_s1[el_[r]][2] * u;
                        }
                    }
                } else { // wave 3: path 3, per-component sums
                    float tv0[4] = {0.f, 0.f, 0.f, 0.f};
                    float tv1[4] = {0.f, 0.f, 0.f, 0.f};
                    float tv2[4] = {0.f, 0.f, 0.f, 0.f};
                    #pragma unroll
                    for (int jj = 0; jj < 4; jj++) {
                        f32x4 d = {0.f, 0.f, 0.f, 0.f};
                        d = __builtin_amdgcn_mfma_f32_16x16x32_bf16(va0, breg[1][0][jj], d, 0, 0, 0);
                        d = __builtin_amdgcn_mfma_f32_16x16x32_bf16(va1, breg[1][1][jj], d, 0, 0, 0);
                        int i = 2 * jj + hi;
                        #pragma unroll
                        for (int r = 0; r < 4; r++) {
                            tv0[r] = fmaf(s_g[el_[r]][8 + 3 * i + 0], d[r], tv0[r]);
                            tv1[r] = fmaf(s_g[el_[r]][8 + 3 * i + 1], d[r], tv1[r]);
                            tv2[r] = fmaf(s_g[el_[r]][8 + 3 * i + 2], d[r], tv2[r]);
                        }
                    }
                    #pragma unroll
                    for (int r = 0; r < 4; r++) {
                        float v0 = tv0[r] + __shfl_xor(tv0[r], 8);
                        float v1 = tv1[r] + __shfl_xor(tv1[r], 8);
                        float v2 = tv2[r] + __shfl_xor(tv2[r], 8);
                        if (n < 8) {
                            s_vB[le_[r]][8 + 3 * o8 + 0] = v0;
                            s_vB[le_[r]][8 + 3 * o8 + 1] = v1;
                            s_vB[le_[r]][8 + 3 * o8 + 2] = v2;
                        }
                    }
                }
            }
        }
        __syncthreads(); // b3: s_lgp complete; s_g/s_s1/s_emb free for next group

        // logit finalize: sum 4 path partials; 0.25 * 1/(8*sqrt2)
        if (t < 16) {
            s_lg[le0 + t] = (s_lgp[t][0] + s_lgp[t][1] + s_lgp[t][2] + s_lgp[t][3])
                            * 0.022097086912079613f;
        }
        // next-iteration phase A may start immediately; b1(g+1) protects s_lgp/s_lg
    }
    __syncthreads(); // final: s_lg / s_vA / s_vB complete for epilogue

    // ---- epilogue: per-node softmax + weighted sum; nrm=0.25 folded in coef ----
    {
        int base_le = DEG * wave;
        int h32 = lane & 32;
        int hl = lane & 31;
        float lg = -INFINITY, cw = 0.0f;
        if (hl < DEG) {
            lg = s_lg[base_le + hl];
            cw = s_cut[base_le + hl];
        }
        float mx = lg;
        mx = fmaxf(mx, __shfl_xor(mx, 16));
        mx = fmaxf(mx, __shfl_xor(mx, 8));
        mx = fmaxf(mx, __shfl_xor(mx, 4));
        mx = fmaxf(mx, __shfl_xor(mx, 2));
        mx = fmaxf(mx, __shfl_xor(mx, 1));

        float ew = cw * __expf(lg - mx);
        float z = ew;
        z += __shfl_xor(z, 16);
        z += __shfl_xor(z, 8);
        z += __shfl_xor(z, 4);
        z += __shfl_xor(z, 2);
        z += __shfl_xor(z, 1);
        z = (z == 0.0f) ? 1.0f : z;
        float coef = sqrtf(ew / z + 1e-12f) * 0.25f;

        float acc = 0.0f;
        #pragma unroll
        for (int ee = 0; ee < DEG; ee++) {
            float ce = __shfl(coef, h32 + ee);
            acc = fmaf(ce, s_vA[base_le + ee][hl] + s_vB[base_le + ee][hl], acc);
        }
        if (lane < 32) out[(size_t)(n0 + wave) * 32 + hl] = acc;
    }
}

// ---------------------------------------------------------------------------
extern "C" void kernel_launch(void* const* d_in, const int* in_sizes, int n_in,
                              void* d_out, int out_size, void* d_ws, size_t ws_size,
                              hipStream_t stream) {
    const float* f    = (const float*)d_in[0];
    const float* pos  = (const float*)d_in[1];
    const float* Wqs  = (const float*)d_in[2];
    const float* Wqv  = (const float*)d_in[3];
    const float* Wk1  = (const float*)d_in[4];
    const float* Wk2  = (const float*)d_in[5];
    const float* Wv1  = (const float*)d_in[6];
    const float* Wv2  = (const float*)d_in[7];
    const float* Wds  = (const float*)d_in[8];
    const float* Wdv  = (const float*)d_in[9];
    const int* esrc   = (const int*)d_in[10];
    float* out        = (float*)d_out;

    edge_kernel<<<dim3(NN / 4), dim3(256), 0, stream>>>(
        f, pos, Wqs, Wqv, Wds, Wdv, Wk1, Wv1, Wk2, Wv2, esrc, out);
}

// Round 3
// 215.337 us; speedup vs baseline: 1.8822x; 1.8822x over previous
//
#include <hip/hip_runtime.h>
#include <hip/hip_bf16.h>
#include <math.h>

#define NN 16384
#define DEG 20
#define EE (NN*DEG)
#define RMAXF 3.5f
#define NGRP 5   // groups of 16 edges per block (80 edges = 4 nodes)

typedef __attribute__((ext_vector_type(8))) short short8;
typedef __attribute__((ext_vector_type(4))) float f32x4;

// soft_unit_step: exp(-1/x) for x>0 else 0
__device__ __forceinline__ float su_f(float x) {
    return x > 0.0f ? __expf(-1.0f / x) : 0.0f;
}
__device__ __forceinline__ ushort f2bf(float x) {
    __hip_bfloat16 h = __float2bfloat16(x);
    return *reinterpret_cast<ushort*>(&h);
}

// ---------------------------------------------------------------------------
// Round-14: exact round-0 structure (proven 188us @ (256,3), 84 VGPR, no
// spill) with two safe deltas:
//  (1) s_w stride 261 -> 260.  Phase-C stores: addr=(4qd+r)*S+tt*16+n;
//      4*261%32=20 -> 3-way bank overlap across qd (measured 1.59e7 conflict
//      cycles = ~14% of block time).  4*260%32=16 -> qd{0,2} vs qd{1,3} hit
//      disjoint 16-bank halves = uniform 2-way = free (m136).  Phase-D reads
//      stay <=2-way (260%32=4).  Row length 260 >= 256 needed.
//  (2) phase A parallelized to 11 roles/edge (176 threads, ~2 expf each)
//      instead of 16 threads x serial 10-iter expf chain.  Same outputs,
//      same barrier structure.
// The round-12/13 fused-MFMA-consumption variant is abandoned: correctness
// flipped with launch-bounds-only changes (regalloc-sensitive), unfixable
// blind.
// Relies on edst[e] == e/20 (contiguous segments; exploited since round 1).
// ---------------------------------------------------------------------------
__global__ __launch_bounds__(256, 3) void edge_kernel(
    const float* __restrict__ f,   const float* __restrict__ pos,
    const float* __restrict__ Wqs, const float* __restrict__ Wqv,
    const float* __restrict__ Wds, const float* __restrict__ Wdv,
    const float* __restrict__ Wk1, const float* __restrict__ Wv1,
    const float* __restrict__ Wk2, const float* __restrict__ Wv2,
    const int* __restrict__ esrc,  float* __restrict__ out)
{
    __shared__ float  s_w[2][16][260];                // 33.3 KB, D matrices (k,v)
    __shared__ __align__(16) ushort s_hb[2][16][64];  // 4 KB bf16 h, XOR-swizzled
    __shared__ __align__(16) float s_g[16][36];       // 2.25 KB, f[src], pad 36
    __shared__ float s_emb[16][10];
    __shared__ float s_s1[16][4];
    __shared__ float s_v[80][33];                     // 10.6 KB, per-edge v
    __shared__ float s_lg[80];                        // per-edge logits
    __shared__ float s_cut[80];                       // per-edge cutoff
    __shared__ float s_mqn[4][32];                    // mq for block's 4 nodes

    const int t = threadIdx.x;
    const int wave = t >> 6, lane = t & 63;
    const int qd = lane >> 4, n = lane & 15;
    const int n0 = blockIdx.x * 4;                    // first node of block
    const int E0 = n0 * DEG;                          // first edge of block

    // ---- prologue A: mq for the block's 4 dst nodes (verbatim prep math) ----
    if (t < 128) {
        int nd = t >> 5, idx = t & 31;
        const float* fr = f + (size_t)(n0 + nd) * 32;
        const float inv8 = 0.35355339059327373f; // 1/sqrt(8)
        float o_ = 0.0f;
        if (idx < 8) {
            int j = idx;
            #pragma unroll
            for (int i = 0; i < 8; i++) {
                float qs = 0.0f;
                #pragma unroll
                for (int a = 0; a < 8; a++) qs = fmaf(fr[a], Wqs[a * 8 + i], qs);
                o_ = fmaf(qs * inv8, Wds[i * 8 + j], o_);
            }
        } else {
            int kk = idx - 8;
            int j = kk / 3, c = kk - 3 * j;
            #pragma unroll
            for (int i = 0; i < 8; i++) {
                float qv = 0.0f;
                #pragma unroll
                for (int a = 0; a < 8; a++) qv = fmaf(fr[8 + 3 * a + c], Wqv[a * 8 + i], qv);
                o_ = fmaf(qv * inv8, Wdv[i * 8 + j], o_);
            }
            o_ *= 0.5773502691896258f; // 1/sqrt(3)
        }
        s_mqn[nd][idx] = o_;
    }

    // ---- prologue B: W1 rows for this lane (20 regs) ----
    float wk1r[10], wv1r[10];
    #pragma unroll
    for (int j = 0; j < 10; j++) {
        wk1r[j] = Wk1[j * 64 + lane];
        wv1r[j] = Wv1[j * 64 + lane];
    }

    // ---- prologue C: B fragments packed directly from W2 (both nets) ----
    // breg[net][s][jj] = 8 bf16: W2[k=s*32+qd*8+j][col=(wave*4+jj)*16+n]*0.125
    short8 breg[2][2][4];
    #pragma unroll
    for (int net = 0; net < 2; net++) {
        const float* W2 = net ? Wv2 : Wk2;
        #pragma unroll
        for (int s = 0; s < 2; s++)
            #pragma unroll
            for (int jj = 0; jj < 4; jj++) {
                int col = (wave * 4 + jj) * 16 + n;
                union { ushort u[8]; short8 v; } bf;
                #pragma unroll
                for (int j = 0; j < 8; j++) {
                    int k0 = s * 32 + qd * 8 + j;
                    bf.u[j] = f2bf(W2[k0 * 256 + col] * 0.125f);
                }
                breg[net][s][jj] = bf.v;
            }
    }

    for (int g = 0; g < NGRP; g++) {
        const int le0 = g * 16;            // local edge base
        const int e0 = E0 + le0;

        // ---- phase A: geometry + radial basis, 11 roles per edge ----
        {
            int e = t >> 4, role = t & 15;
            if (role < 11) {
                int s = esrc[e0 + e];
                int d = n0 + (le0 + e) / DEG;  // edst[e] == e/20
                float vx = pos[s * 3 + 0] - pos[d * 3 + 0];
                float vy = pos[s * 3 + 1] - pos[d * 3 + 1];
                float vz = pos[s * 3 + 2] - pos[d * 3 + 2];
                float r = sqrtf(vx * vx + vy * vy + vz * vz);
                if (role < 10) {
                    const float step = RMAXF / 11.0f;
                    const float invstep = 11.0f / RMAXF;
                    const float K = 26.66929988626f; // 1.14136*e^2*sqrt(10)
                    float dd = (r - step * (float)(role + 1)) * invstep;
                    s_emb[e][role] = K * su_f(dd + 1.0f) * su_f(1.0f - dd);
                } else {
                    float invr = 1.0f / r;
                    const float sqrt3 = 1.7320508075688772f;
                    s_s1[e][0] = sqrt3 * vx * invr;
                    s_s1[e][1] = sqrt3 * vy * invr;
                    s_s1[e][2] = sqrt3 * vz * invr;
                    s_cut[le0 + e] = su_f(10.0f * (1.0f - r / RMAXF));
                }
            }
        }
        // ---- phase A2: stage gathered f[src] rows (float4, threads 0..127) ----
        if (t < 128) {
            int el = t >> 3, c4 = t & 7;
            int s = esrc[e0 + el];
            float4 x = *reinterpret_cast<const float4*>(f + (size_t)s * 32 + c4 * 4);
            *reinterpret_cast<float4*>(&s_g[el][c4 * 4]) = x;
        }
        __syncthreads(); // barrier 1

        // ---- phase B: GEMM1 (W1 in regs) + silu (both nets) -> s_hb ----
        {
            const float invsq10 = 0.31622776601683794f; // 1/sqrt(10)
            #pragma unroll
            for (int e = 0; e < 4; e++) {
                int el = wave * 4 + e;
                float ak = 0.0f, av = 0.0f;
                #pragma unroll
                for (int j = 0; j < 10; j++) {
                    float ej = s_emb[el][j];
                    ak = fmaf(ej, wk1r[j], ak);
                    av = fmaf(ej, wv1r[j], av);
                }
                ak *= invsq10; av *= invsq10;
                float hk = ak / (1.0f + __expf(-ak));
                float hv = av / (1.0f + __expf(-av));
                int pos_ = ((((lane >> 3) ^ (el & 7))) << 3) | (lane & 7);
                s_hb[0][el][pos_] = f2bf(hk);
                s_hb[1][el][pos_] = f2bf(hv);
            }
        }
        __syncthreads(); // barrier 2

        // ---- phase C: MFMA GEMM2 for both nets -> s_w[net] ----
        #pragma unroll
        for (int net = 0; net < 2; net++) {
            short8 ha0 = *(const short8*)&s_hb[net][n][((qd ^ (n & 7)) << 3)];
            short8 ha1 = *(const short8*)&s_hb[net][n][(((4 + qd) ^ (n & 7)) << 3)];
            #pragma unroll
            for (int jj = 0; jj < 4; jj++) {
                int tt = wave * 4 + jj;
                f32x4 d = {0.0f, 0.0f, 0.0f, 0.0f};
                d = __builtin_amdgcn_mfma_f32_16x16x32_bf16(ha0, breg[net][0][jj], d, 0, 0, 0);
                d = __builtin_amdgcn_mfma_f32_16x16x32_bf16(ha1, breg[net][1][jj], d, 0, 0, 0);
                #pragma unroll
                for (int r = 0; r < 4; r++)
                    s_w[net][4 * qd + r][tt * 16 + n] = d[r]; // D: row=4*quad+reg, col=n
            }
        }
        __syncthreads(); // barrier 3

        // ---- phase D: s_g via float4; k-net TP + mq-logits; v-net TP ----
        {
            int el = t >> 4, role = t & 15;
            int le = le0 + el;
            int nd = le / DEG;             // local dst node of this edge
            float s1x = s_s1[el][0], s1y = s_s1[el][1], s1z = s_s1[el][2];
            const float inv_sqrt3 = 0.5773502691896258f;
            float g[32];
            #pragma unroll
            for (int v4 = 0; v4 < 8; v4++) {
                float4 x = *reinterpret_cast<const float4*>(&s_g[el][v4 * 4]);
                g[v4 * 4 + 0] = x.x; g[v4 * 4 + 1] = x.y;
                g[v4 * 4 + 2] = x.z; g[v4 * 4 + 3] = x.w;
            }
            float a[8], b[8];
            #pragma unroll
            for (int i = 0; i < 8; i++) {
                a[i] = g[i];
                b[i] = (g[8 + i * 3 + 0] * s1x +
                        g[8 + i * 3 + 1] * s1y +
                        g[8 + i * 3 + 2] * s1z) * inv_sqrt3;
            }
            const float nrm = 0.25f; // 1/(sqrt(8)*sqrt(2))

            // --- k-net: this role's ks/kv contracted with mq ---
            const float* wk = s_w[0][el];
            float contrib = 0.0f;
            if (role < 8) {
                int o = role;
                float ks = 0.0f;
                #pragma unroll
                for (int i = 0; i < 8; i++)
                    ks += a[i] * wk[i * 8 + o] + b[i] * wk[64 + i * 8 + o];
                contrib = s_mqn[nd][o] * (ks * nrm);
            } else {
                int o = role - 8;
                #pragma unroll
                for (int c = 0; c < 3; c++) {
                    float uk = 0.0f, tk = 0.0f;
                    #pragma unroll
                    for (int i = 0; i < 8; i++) {
                        uk += a[i] * wk[128 + i * 8 + o];
                        tk = fmaf(g[8 + i * 3 + c], wk[192 + i * 8 + o], tk);
                    }
                    float kv_c = nrm * (s_s1[el][c] * uk + tk);
                    contrib = fmaf(s_mqn[nd][8 + 3 * o + c], kv_c, contrib);
                }
            }
            contrib += __shfl_xor(contrib, 1);
            contrib += __shfl_xor(contrib, 2);
            contrib += __shfl_xor(contrib, 4);
            contrib += __shfl_xor(contrib, 8);
            if (role == 0) s_lg[le] = contrib * 0.08838834764831845f; // 1/(8*sqrt2)

            // --- v-net TP -> s_v ---
            const float* wv = s_w[1][el];
            if (role < 8) {
                int o = role;
                float vs = 0.0f;
                #pragma unroll
                for (int i = 0; i < 8; i++)
                    vs += a[i] * wv[i * 8 + o] + b[i] * wv[64 + i * 8 + o];
                s_v[le][o] = vs * nrm;
            } else {
                int o = role - 8;
                #pragma unroll
                for (int c = 0; c < 3; c++) {
                    float uv = 0.0f, tv = 0.0f;
                    #pragma unroll
                    for (int i = 0; i < 8; i++) {
                        uv += a[i] * wv[128 + i * 8 + o];
                        tv = fmaf(g[8 + i * 3 + c], wv[192 + i * 8 + o], tv);
                    }
                    s_v[le][8 + o * 3 + c] = nrm * (s_s1[el][c] * uv + tv);
                }
            }
        }
        __syncthreads(); // barrier 4: protects s_* for next group / epilogue
    }

    // ---- epilogue: per-node softmax + weighted sum (proven out_kernel math).
    //      wave w handles node n0+w; both 32-lane halves compute identically.
    {
        int base_le = DEG * wave;
        int h32 = lane & 32;
        int hl = lane & 31;
        float lg = -INFINITY, cw = 0.0f;
        if (hl < DEG) {
            lg = s_lg[base_le + hl];
            cw = s_cut[base_le + hl];
        }
        float mx = lg;
        mx = fmaxf(mx, __shfl_xor(mx, 16));
        mx = fmaxf(mx, __shfl_xor(mx, 8));
        mx = fmaxf(mx, __shfl_xor(mx, 4));
        mx = fmaxf(mx, __shfl_xor(mx, 2));
        mx = fmaxf(mx, __shfl_xor(mx, 1));

        float ew = cw * __expf(lg - mx);
        float z = ew;
        z += __shfl_xor(z, 16);
        z += __shfl_xor(z, 8);
        z += __shfl_xor(z, 4);
        z += __shfl_xor(z, 2);
        z += __shfl_xor(z, 1);
        z = (z == 0.0f) ? 1.0f : z;
        float coef = sqrtf(ew / z + 1e-12f);

        float acc = 0.0f;
        #pragma unroll
        for (int ee = 0; ee < DEG; ee++) {
            float ce = __shfl(coef, h32 + ee);
            acc = fmaf(ce, s_v[base_le + ee][hl], acc);
        }
        if (lane < 32) out[(size_t)(n0 + wave) * 32 + hl] = acc;
    }
}

// ---------------------------------------------------------------------------
extern "C" void kernel_launch(void* const* d_in, const int* in_sizes, int n_in,
                              void* d_out, int out_size, void* d_ws, size_t ws_size,
                              hipStream_t stream) {
    const float* f    = (const float*)d_in[0];
    const float* pos  = (const float*)d_in[1];
    const float* Wqs  = (const float*)d_in[2];
    const float* Wqv  = (const float*)d_in[3];
    const float* Wk1  = (const float*)d_in[4];
    const float* Wk2  = (const float*)d_in[5];
    const float* Wv1  = (const float*)d_in[6];
    const float* Wv2  = (const float*)d_in[7];
    const float* Wds  = (const float*)d_in[8];
    const float* Wdv  = (const float*)d_in[9];
    const int* esrc   = (const int*)d_in[10];
    float* out        = (float*)d_out;

    edge_kernel<<<dim3(NN / 4), dim3(256), 0, stream>>>(
        f, pos, Wqs, Wqv, Wds, Wdv, Wk1, Wv1, Wk2, Wv2, esrc, out);
}